// Round 3
// baseline (711.789 us; speedup 1.0000x reference)
//
#include <hip/hip_runtime.h>

// ---- problem constants ----
// B=2, T=2048, TREF=512, C=768, H=12, D=64, L=T+TREF=2560

typedef __bf16 bf16x8 __attribute__((ext_vector_type(8)));
typedef float floatx4 __attribute__((ext_vector_type(4)));

__device__ __forceinline__ ushort f2bf(float f) {
  uint u = __builtin_bit_cast(uint, f);
  return (ushort)((u + 0x7FFFu + ((u >> 16) & 1u)) >> 16);
}
__device__ __forceinline__ float bf2f(ushort u) {
  return __builtin_bit_cast(float, (uint)u << 16);
}

// async global->LDS, 16B per lane; LDS dest = wave-uniform base + lane*16
__device__ __forceinline__ void gld16(ushort* lds, const ushort* g) {
  __builtin_amdgcn_global_load_lds(
      (const __attribute__((address_space(1))) unsigned int*)g,
      (__attribute__((address_space(3))) unsigned int*)lds, 16, 0, 0);
}

// ---------------- cast kernel: fp32 -> bf16 for x, ref_feat, 6 weights ----------------
__global__ __launch_bounds__(256) void cast_all(
    const float* __restrict__ x, const float* __restrict__ rf,
    const float* __restrict__ w0, const float* __restrict__ w1,
    const float* __restrict__ w2, const float* __restrict__ w3,
    const float* __restrict__ w4, const float* __restrict__ w5,
    ushort* __restrict__ dst) {
  size_t i4 = ((size_t)blockIdx.x * 256 + threadIdx.x) * 4;
  const float* src;
  size_t off;
  if (i4 < 3145728) { src = x; off = i4; }
  else if (i4 < 3932160) { src = rf; off = i4 - 3145728; }
  else {
    size_t r = i4 - 3932160;
    if (r < 589824) { src = w0; off = r; }
    else if (r < 2 * 589824) { src = w1; off = r - 589824; }
    else if (r < 3 * 589824) { src = w2; off = r - 2 * 589824; }
    else if (r < 4 * 589824) { src = w3; off = r - 3 * 589824; }
    else if (r < 5 * 589824) { src = w4; off = r - 4 * 589824; }
    else { src = w5; off = r - 5 * 589824; }
  }
  float4 v = *(const float4*)(src + off);
  ushort4 o;
  o.x = f2bf(v.x); o.y = f2bf(v.y); o.z = f2bf(v.z); o.w = f2bf(v.w);
  *(ushort4*)(dst + i4) = o;
}

// ---------------- mask bit-pack: mask[b][t][2048] int32 -> bits[b][t][32] u64 ----------------
__global__ __launch_bounds__(256) void pack_mask(
    const int* __restrict__ mask, unsigned long long* __restrict__ bits) {
  const int gid = blockIdx.x * 256 + threadIdx.x;  // [0, 131072)
  const int4* src = (const int4*)(mask + (size_t)gid * 64);
  unsigned long long v = 0;
#pragma unroll
  for (int j = 0; j < 16; ++j) {
    int4 m = src[j];
    unsigned long long nib = (m.x ? 1ull : 0ull) | (m.y ? 2ull : 0ull) |
                             (m.z ? 4ull : 0ull) | (m.w ? 8ull : 0ull);
    v |= nib << (j * 4);
  }
  bits[gid] = v;
}

// ---------------- shared GEMM core: 128x128 tile, K=768, m97-style gl_lds ----------------
__device__ __forceinline__ void gemm_core(
    const ushort* __restrict__ Ab, const ushort* __restrict__ Bb,
    ushort* As, ushort* Bs, int tid, int quad, int l16, int mw, int nw,
    floatx4 acc[4][4]) {
  const int w = tid >> 6;
  const int r0 = tid >> 2, kp = (tid & 3) * 8;
  const size_t ga0 = (size_t)r0 * 768 + kp;
  const size_t ga1 = ga0 + (size_t)64 * 768;
  ushort* lA0 = &As[w * 512];         // lane*16B implicit
  ushort* lA1 = &As[w * 512 + 2048];
  ushort* lB0 = &Bs[w * 512];
  ushort* lB1 = &Bs[w * 512 + 2048];
#pragma unroll 1
  for (int kb = 0; kb < 24; ++kb) {
    const int k0 = kb * 32;
    gld16(lA0, Ab + ga0 + k0);
    gld16(lA1, Ab + ga1 + k0);
    gld16(lB0, Bb + ga0 + k0);
    gld16(lB1, Bb + ga1 + k0);
    __syncthreads();  // drains gl_lds -> tile in LDS
    bf16x8 af[4], bfr[4];
#pragma unroll
    for (int mt = 0; mt < 4; ++mt)
      af[mt] = *(const bf16x8*)&As[(mw + mt * 16 + l16) * 32 + quad * 8];
#pragma unroll
    for (int nt = 0; nt < 4; ++nt)
      bfr[nt] = *(const bf16x8*)&Bs[(nw + nt * 16 + l16) * 32 + quad * 8];
#pragma unroll
    for (int mt = 0; mt < 4; ++mt)
#pragma unroll
      for (int nt = 0; nt < 4; ++nt)
        acc[mt][nt] = __builtin_amdgcn_mfma_f32_16x16x32_bf16(af[mt], bfr[nt], acc[mt][nt], 0, 0, 0);
    __syncthreads();  // everyone done reading before next writes
  }
}

// ---------------- fused projection GEMMs ----------------
template <int REF>
__global__ __launch_bounds__(256) void gemm_fused(
    const ushort* __restrict__ A, const ushort* __restrict__ W,
    const float* __restrict__ bA, const float* __restrict__ bB,
    const float* __restrict__ bC,
    ushort* __restrict__ oA, ushort* __restrict__ oB, ushort* __restrict__ oC) {
  const int bm = blockIdx.x, bn = blockIdx.y;
  const int tid = threadIdx.x;
  const int w = tid >> 6, lane = tid & 63, quad = lane >> 4, l16 = lane & 15;
  const int mw = (w >> 1) * 64, nw = (w & 1) * 64;

  __shared__ __align__(16) ushort As[128 * 32];
  __shared__ __align__(16) ushort Bs[128 * 32];

  floatx4 acc[4][4];
#pragma unroll
  for (int mt = 0; mt < 4; ++mt)
#pragma unroll
    for (int nt = 0; nt < 4; ++nt) acc[mt][nt] = (floatx4){0.f, 0.f, 0.f, 0.f};

  gemm_core(A + (size_t)bm * 128 * 768, W + (size_t)bn * 128 * 768,
            As, Bs, tid, quad, l16, mw, nw, acc);

  const int sec = bn / 6;
  const float* bp = sec == 0 ? bA : sec == 1 ? bB : bC;
  ushort* op = sec == 0 ? oA : sec == 1 ? oB : oC;
  const bool qlay = (REF == 0 && sec == 0);
#pragma unroll
  for (int nt = 0; nt < 4; ++nt) {
    const int nloc = (bn - sec * 6) * 128 + nw + nt * 16 + l16;
    const float bv = bp[nloc];
    const int hh = nloc >> 6, dd = nloc & 63;
#pragma unroll
    for (int mt = 0; mt < 4; ++mt)
#pragma unroll
      for (int i = 0; i < 4; ++i) {
        const int m = bm * 128 + mw + mt * 16 + quad * 4 + i;
        int bb, tt;
        if (REF == 0) { bb = m >> 11; tt = m & 2047; }
        else { bb = m >> 9; tt = (m & 511) + 2048; }
        const size_t idx = qlay ? (((size_t)(bb * 12 + hh) * 2048 + tt) * 64 + dd)
                                : (((size_t)(bb * 12 + hh) * 2560 + tt) * 64 + dd);
        op[idx] = f2bf(acc[mt][nt][i] + bv);
      }
  }
}

// ---------------- output projection: fp32 out ----------------
__global__ __launch_bounds__(256) void gemm_out(
    const ushort* __restrict__ A, const ushort* __restrict__ W,
    const float* __restrict__ bias, float* __restrict__ out) {
  const int bm = blockIdx.x, bn = blockIdx.y;
  const int tid = threadIdx.x;
  const int w = tid >> 6, lane = tid & 63, quad = lane >> 4, l16 = lane & 15;
  const int mw = (w >> 1) * 64, nw = (w & 1) * 64;

  __shared__ __align__(16) ushort As[128 * 32];
  __shared__ __align__(16) ushort Bs[128 * 32];

  floatx4 acc[4][4];
#pragma unroll
  for (int mt = 0; mt < 4; ++mt)
#pragma unroll
    for (int nt = 0; nt < 4; ++nt) acc[mt][nt] = (floatx4){0.f, 0.f, 0.f, 0.f};

  gemm_core(A + (size_t)bm * 128 * 768, W + (size_t)bn * 128 * 768,
            As, Bs, tid, quad, l16, mw, nw, acc);

#pragma unroll
  for (int nt = 0; nt < 4; ++nt) {
    const int n = bn * 128 + nw + nt * 16 + l16;
    const float bv = bias[n];
#pragma unroll
    for (int mt = 0; mt < 4; ++mt)
#pragma unroll
      for (int i = 0; i < 4; ++i) {
        const int m = bm * 128 + mw + mt * 16 + quad * 4 + i;
        out[(size_t)m * 768 + n] = acc[mt][nt][i] + bv;
      }
  }
}

// ---------------- flash attention v3: 128-key tiles, bit-mask, aliased LDS ----------------
// grid (B, T/64, H), 256 threads = 4 waves; wave w owns q-rows [w*16,w*16+16).
// S^T = K.Q^T (lane owns q-column l16). Per 128-key tile: K/V via VGPR prefetch,
// rel fp32 global -> bf16 LDS, mask from prepacked bitwords in registers.
// LDS aliasing: Q staged in Ks (consumed before tile0 write); P^T overwrites the
// rel rows (each wave touches only its own 16 rows for both).
__global__ __launch_bounds__(256, 3) void attn(
    const ushort* __restrict__ qb, const ushort* __restrict__ kb,
    const ushort* __restrict__ vb, const unsigned long long* __restrict__ bits,
    const float* __restrict__ relp, ushort* __restrict__ yb) {
  const int b = blockIdx.x, qt = blockIdx.y, h = blockIdx.z;
  const int tid = threadIdx.x;
  const int w = tid >> 6, lane = tid & 63, quad = lane >> 4, l16 = lane & 15;

  __shared__ __align__(16) ushort Ks[128 * 72];   // keys x d, stride 72 (Q staged here first)
  __shared__ __align__(16) ushort Vs[64 * 128];   // [d][key'] xor-swizzled per 64-half
  __shared__ __align__(16) ushort RPs[64 * 136];  // rel bf16 tile, then per-wave P^T

  const ushort* qsrc = qb + ((size_t)(b * 12 + h) * 2048 + qt * 64) * 64;
  const ushort* ksrc = kb + (size_t)(b * 12 + h) * 2560 * 64;
  const ushort* vsrc = vb + (size_t)(b * 12 + h) * 2560 * 64;
  const int qrow = qt * 64 + w * 16 + l16;
  const unsigned long long* brow = bits + ((size_t)b * 2048 + qrow) * 32;
  const float* rbase = relp + ((size_t)h * 2048 + qt * 64) * 2048;

  // ---- stage Q into Ks area ----
#pragma unroll
  for (int c = 0; c < 2; ++c) {
    const int f = tid + c * 256;
    *(uint4*)&Ks[(f >> 3) * 72 + (f & 7) * 8] = *(const uint4*)(qsrc + f * 8);
  }
  // ---- prefetch tile 0 ----
  uint4 kreg[4], vreg[4];
  float4 rreg[8];
  ulonglong2 breg;
  {
#pragma unroll
    for (int c = 0; c < 4; ++c) {
      const int f = tid + c * 256;
      kreg[c] = *(const uint4*)(ksrc + f * 8);
      vreg[c] = *(const uint4*)(vsrc + f * 8);
    }
#pragma unroll
    for (int p = 0; p < 8; ++p) {
      const int f4 = tid + p * 256, row = f4 >> 5, c4 = f4 & 31;
      rreg[p] = *(const float4*)(rbase + (size_t)row * 2048 + c4 * 4);
    }
    breg = *(const ulonglong2*)brow;
  }
  __syncthreads();  // Q staged
  bf16x8 bQ[2];
  bQ[0] = *(const bf16x8*)&Ks[(w * 16 + l16) * 72 + quad * 8];
  bQ[1] = *(const bf16x8*)&Ks[(w * 16 + l16) * 72 + 32 + quad * 8];

  floatx4 acc[4];
#pragma unroll
  for (int mt = 0; mt < 4; ++mt) acc[mt] = (floatx4){0.f, 0.f, 0.f, 0.f};
  float m_run = -__builtin_inff(), l_run = 0.f;

#pragma unroll 1
  for (int it = 0; it < 20; ++it) {
    const bool self = it < 16;
    __syncthreads();  // all waves done reading previous tile (and bQ at it=0)
    // ---- write tile it from regs ----
#pragma unroll
    for (int c = 0; c < 4; ++c) {
      const int f = tid + c * 256;
      *(uint4*)&Ks[(f >> 3) * 72 + (f & 7) * 8] = kreg[c];
      const int key = f >> 3, d0 = (f & 7) * 8;
      const int kh = key & 63, half = key >> 6;
      const int col = half * 64 + (((kh >> 3) ^ (f & 7)) & 7) * 8 + (kh & 7);
      uint vv[4] = {vreg[c].x, vreg[c].y, vreg[c].z, vreg[c].w};
#pragma unroll
      for (int u = 0; u < 4; ++u) {
        Vs[(d0 + 2 * u) * 128 + col] = (ushort)(vv[u] & 0xffffu);
        Vs[(d0 + 2 * u + 1) * 128 + col] = (ushort)(vv[u] >> 16);
      }
    }
    if (self) {
#pragma unroll
      for (int p = 0; p < 8; ++p) {
        const int f4 = tid + p * 256, row = f4 >> 5, c4 = f4 & 31;
        uint2 pk;
        pk.x = (uint)f2bf(rreg[p].x) | ((uint)f2bf(rreg[p].y) << 16);
        pk.y = (uint)f2bf(rreg[p].z) | ((uint)f2bf(rreg[p].w) << 16);
        *(uint2*)&RPs[row * 136 + c4 * 4] = pk;
      }
    }
    __syncthreads();  // tile it visible
    const ulonglong2 bcur = breg;
    // ---- prefetch tile it+1 (consumed next iter; full compute phase to land) ----
    const int itn = it + 1;
    if (itn < 20) {
      const ushort* kt0 = ksrc + itn * 8192;
      const ushort* vt0 = vsrc + itn * 8192;
#pragma unroll
      for (int c = 0; c < 4; ++c) {
        const int f = tid + c * 256;
        kreg[c] = *(const uint4*)(kt0 + f * 8);
        vreg[c] = *(const uint4*)(vt0 + f * 8);
      }
      if (itn < 16) {
#pragma unroll
        for (int p = 0; p < 8; ++p) {
          const int f4 = tid + p * 256, row = f4 >> 5, c4 = f4 & 31;
          rreg[p] = *(const float4*)(rbase + (size_t)row * 2048 + itn * 128 + c4 * 4);
        }
        breg = *(const ulonglong2*)(brow + itn * 2);
      }
    }

    // ---- S^T = K.Q^T : lane holds S^T[key = mt*16+quad*4+i][qr=l16] ----
    floatx4 st[8];
#pragma unroll
    for (int mt = 0; mt < 8; ++mt) st[mt] = (floatx4){0.f, 0.f, 0.f, 0.f};
#pragma unroll
    for (int kk = 0; kk < 2; ++kk)
#pragma unroll
      for (int mt = 0; mt < 8; ++mt) {
        bf16x8 aK = *(const bf16x8*)&Ks[(mt * 16 + l16) * 72 + kk * 32 + quad * 8];
        st[mt] = __builtin_amdgcn_mfma_f32_16x16x32_bf16(aK, bQ[kk], st[mt], 0, 0, 0);
      }
    // ---- scale + bias + mask ----
#pragma unroll
    for (int mt = 0; mt < 8; ++mt) {
      if (self) {
        const ushort4 rv4 = *(const ushort4*)&RPs[(w * 16 + l16) * 136 + mt * 16 + quad * 4];
        const ushort rv[4] = {rv4.x, rv4.y, rv4.z, rv4.w};
        const unsigned long long word = (mt < 4) ? bcur.x : bcur.y;
#pragma unroll
        for (int i = 0; i < 4; ++i) {
          float sv = st[mt][i] * 0.125f + bf2f(rv[i]);
          const int bit = (mt & 3) * 16 + quad * 4 + i;
          st[mt][i] = ((word >> bit) & 1ull) ? -__builtin_inff() : sv;
        }
      } else {
#pragma unroll
        for (int i = 0; i < 4; ++i) st[mt][i] *= 0.125f;
      }
    }
    // ---- online softmax (per q-column l16) ----
    float tm = st[0][0];
#pragma unroll
    for (int mt = 0; mt < 8; ++mt)
#pragma unroll
      for (int i = 0; i < 4; ++i) tm = fmaxf(tm, st[mt][i]);
    tm = fmaxf(tm, __shfl_xor(tm, 16));
    tm = fmaxf(tm, __shfl_xor(tm, 32));
    const float mnew = fmaxf(m_run, tm);
    const float mref = (mnew == -__builtin_inff()) ? 0.f : mnew;
    const float alpha = (m_run == -__builtin_inff()) ? 0.f : __expf(m_run - mnew);
    float rs = 0.f;
#pragma unroll
    for (int mt = 0; mt < 8; ++mt)
#pragma unroll
      for (int i = 0; i < 4; ++i) {
        const float pv = __expf(st[mt][i] - mref);
        st[mt][i] = pv;
        rs += pv;
      }
    rs += __shfl_xor(rs, 16);
    rs += __shfl_xor(rs, 32);
    l_run = l_run * alpha + rs;
    m_run = mnew;
#pragma unroll
    for (int mt = 0; mt < 4; ++mt)
#pragma unroll
      for (int i = 0; i < 4; ++i) acc[mt][i] *= alpha;

    // ---- P^T -> RPs rows (this wave's own 16 rows; overwrites consumed rel) ----
    {
      ushort* pw = &RPs[(w * 16 + l16) * 136];
#pragma unroll
      for (int mt = 0; mt < 8; ++mt) {
        uint2 pk;
        pk.x = (uint)f2bf(st[mt][0]) | ((uint)f2bf(st[mt][1]) << 16);
        pk.y = (uint)f2bf(st[mt][2]) | ((uint)f2bf(st[mt][3]) << 16);
        *(uint2*)&pw[mt * 16 + quad * 4] = pk;
      }
    }
    // ---- O^T += V^T . P^T ----
#pragma unroll
    for (int kk = 0; kk < 4; ++kk) {
      const bf16x8 bP = *(const bf16x8*)&RPs[(w * 16 + l16) * 136 + kk * 32 + quad * 8];
#pragma unroll
      for (int mt = 0; mt < 4; ++mt) {
        const int dd = mt * 16 + l16;
        const int cs = ((((kk & 1) * 4 + quad) ^ (dd >> 3)) & 7) * 8;
        const bf16x8 aV = *(const bf16x8*)&Vs[dd * 128 + (kk >> 1) * 64 + cs];
        acc[mt] = __builtin_amdgcn_mfma_f32_16x16x32_bf16(aV, bP, acc[mt], 0, 0, 0);
      }
    }
  }

  // ---- epilogue: y[b][t][h*64+d] bf16 ----
  const float inv = 1.f / l_run;
  ushort* yrow = yb + ((size_t)b * 2048 + qt * 64 + w * 16 + l16) * 768 + h * 64;
#pragma unroll
  for (int mt = 0; mt < 4; ++mt)
#pragma unroll
    for (int i = 0; i < 4; ++i)
      yrow[mt * 16 + quad * 4 + i] = f2bf(acc[mt][i] * inv);
}

// ---------------- launch ----------------
extern "C" void kernel_launch(void* const* d_in, const int* in_sizes, int n_in,
                              void* d_out, int out_size, void* d_ws, size_t ws_size,
                              hipStream_t stream) {
  const float* x = (const float*)d_in[0];
  const int* mask = (const int*)d_in[1];
  const float* relp = (const float*)d_in[2];
  const float* ref = (const float*)d_in[3];
  const float* Wq = (const float*)d_in[4];
  const float* bq = (const float*)d_in[5];
  const float* Wk = (const float*)d_in[6];
  const float* bk = (const float*)d_in[7];
  const float* Wv = (const float*)d_in[8];
  const float* bv = (const float*)d_in[9];
  const float* Wrk = (const float*)d_in[10];
  const float* brk = (const float*)d_in[11];
  const float* Wrv = (const float*)d_in[12];
  const float* brv = (const float*)d_in[13];
  const float* Wo = (const float*)d_in[14];
  const float* bo = (const float*)d_in[15];

  ushort* xb = (ushort*)d_ws;                 // 3,145,728
  ushort* refb = xb + 3145728;                // 786,432
  ushort* wb = refb + 786432;                 // 6 * 589,824  (q,k,v,rk,rv,o)
  ushort* qbuf = wb + 6 * 589824;             // 3,145,728   [b][h][t][d]
  ushort* kbuf = qbuf + 3145728;              // 3,932,160   [b][h][key][d], L=2560
  ushort* vbuf = kbuf + 3932160;              // 3,932,160
  ushort* ybuf = vbuf + 3932160;              // 3,145,728   [b][t][c]
  unsigned long long* bitsbuf = (unsigned long long*)(ybuf + 3145728);  // 131072 u64

  cast_all<<<7296, 256, 0, stream>>>(x, ref, Wq, Wk, Wv, Wrk, Wrv, Wo, xb);
  pack_mask<<<512, 256, 0, stream>>>(mask, bitsbuf);

  gemm_fused<0><<<dim3(32, 18), 256, 0, stream>>>(
      xb, wb, bq, bk, bv, qbuf, kbuf, vbuf);
  gemm_fused<1><<<dim3(8, 12), 256, 0, stream>>>(
      refb, wb + (size_t)3 * 589824, brk, brv, nullptr, kbuf, vbuf, nullptr);

  attn<<<dim3(2, 32, 12), 256, 0, stream>>>(qbuf, kbuf, vbuf, bitsbuf, relp, ybuf);

  gemm_out<<<dim3(32, 6), 256, 0, stream>>>(
      ybuf, wb + (size_t)5 * 589824, bo, (float*)d_out);
}

// Round 4
// 481.562 us; speedup vs baseline: 1.4781x; 1.4781x over previous
//
#include <hip/hip_runtime.h>

// ---- problem constants ----
// B=2, T=2048, TREF=512, C=768, H=12, D=64, L=T+TREF=2560

typedef __bf16 bf16x8 __attribute__((ext_vector_type(8)));
typedef float floatx4 __attribute__((ext_vector_type(4)));

__device__ __forceinline__ ushort f2bf(float f) {
  uint u = __builtin_bit_cast(uint, f);
  return (ushort)((u + 0x7FFFu + ((u >> 16) & 1u)) >> 16);
}
__device__ __forceinline__ float bf2f(ushort u) {
  return __builtin_bit_cast(float, (uint)u << 16);
}

// async global->LDS, 16B per lane; LDS dest = wave-uniform base + lane*16
__device__ __forceinline__ void gld16(ushort* lds, const ushort* g) {
  __builtin_amdgcn_global_load_lds(
      (const __attribute__((address_space(1))) unsigned int*)g,
      (__attribute__((address_space(3))) unsigned int*)lds, 16, 0, 0);
}

// ---------------- cast kernel: fp32 -> bf16 for x, ref_feat, 6 weights ----------------
__global__ __launch_bounds__(256) void cast_all(
    const float* __restrict__ x, const float* __restrict__ rf,
    const float* __restrict__ w0, const float* __restrict__ w1,
    const float* __restrict__ w2, const float* __restrict__ w3,
    const float* __restrict__ w4, const float* __restrict__ w5,
    ushort* __restrict__ dst) {
  size_t i4 = ((size_t)blockIdx.x * 256 + threadIdx.x) * 4;
  const float* src;
  size_t off;
  if (i4 < 3145728) { src = x; off = i4; }
  else if (i4 < 3932160) { src = rf; off = i4 - 3145728; }
  else {
    size_t r = i4 - 3932160;
    if (r < 589824) { src = w0; off = r; }
    else if (r < 2 * 589824) { src = w1; off = r - 589824; }
    else if (r < 3 * 589824) { src = w2; off = r - 2 * 589824; }
    else if (r < 4 * 589824) { src = w3; off = r - 3 * 589824; }
    else if (r < 5 * 589824) { src = w4; off = r - 4 * 589824; }
    else { src = w5; off = r - 5 * 589824; }
  }
  float4 v = *(const float4*)(src + off);
  ushort4 o;
  o.x = f2bf(v.x); o.y = f2bf(v.y); o.z = f2bf(v.z); o.w = f2bf(v.w);
  *(ushort4*)(dst + i4) = o;
}

// ---------------- mask bit-pack: mask[b][t][2048] int32 -> bits[b][t][32] u64 ----------------
__global__ __launch_bounds__(256) void pack_mask(
    const int* __restrict__ mask, unsigned long long* __restrict__ bits) {
  const int gid = blockIdx.x * 256 + threadIdx.x;  // [0, 131072)
  const int4* src = (const int4*)(mask + (size_t)gid * 64);
  unsigned long long v = 0;
#pragma unroll
  for (int j = 0; j < 16; ++j) {
    int4 m = src[j];
    unsigned long long nib = (m.x ? 1ull : 0ull) | (m.y ? 2ull : 0ull) |
                             (m.z ? 4ull : 0ull) | (m.w ? 8ull : 0ull);
    v |= nib << (j * 4);
  }
  bits[gid] = v;
}

// ---------------- shared GEMM core: 128x128 tile, K=768, gld16 double-buffered ----------------
// As/Bs are 2 x 4096 ushorts each. One barrier per K-iter; gld16 for kb+1 issued
// right after the barrier so its latency overlaps compute of kb.
__device__ __forceinline__ void gemm_core(
    const ushort* __restrict__ Ab, const ushort* __restrict__ Bb,
    ushort* As, ushort* Bs, int tid, int quad, int l16, int mw, int nw,
    floatx4 acc[4][4]) {
  const int w = tid >> 6;
  const int r0 = tid >> 2, kp = (tid & 3) * 8;
  const size_t ga0 = (size_t)r0 * 768 + kp;
  const size_t ga1 = ga0 + (size_t)64 * 768;
  // issue tile kb into buffer p
#define GEMM_ISSUE(kb, p)                                   \
  do {                                                      \
    const int k0_ = (kb) * 32;                              \
    gld16(&As[(p) * 4096 + w * 512], Ab + ga0 + k0_);       \
    gld16(&As[(p) * 4096 + w * 512 + 2048], Ab + ga1 + k0_);\
    gld16(&Bs[(p) * 4096 + w * 512], Bb + ga0 + k0_);       \
    gld16(&Bs[(p) * 4096 + w * 512 + 2048], Bb + ga1 + k0_);\
  } while (0)
  GEMM_ISSUE(0, 0);
#pragma unroll 1
  for (int kb = 0; kb < 24; ++kb) {
    __syncthreads();  // drains gld16(kb); all waves done reading buffer (kb+1)&1
    if (kb < 23) GEMM_ISSUE(kb + 1, (kb + 1) & 1);
    const int p = kb & 1;
    bf16x8 af[4], bfr[4];
#pragma unroll
    for (int mt = 0; mt < 4; ++mt)
      af[mt] = *(const bf16x8*)&As[p * 4096 + (mw + mt * 16 + l16) * 32 + quad * 8];
#pragma unroll
    for (int nt = 0; nt < 4; ++nt)
      bfr[nt] = *(const bf16x8*)&Bs[p * 4096 + (nw + nt * 16 + l16) * 32 + quad * 8];
#pragma unroll
    for (int mt = 0; mt < 4; ++mt)
#pragma unroll
      for (int nt = 0; nt < 4; ++nt)
        acc[mt][nt] = __builtin_amdgcn_mfma_f32_16x16x32_bf16(af[mt], bfr[nt], acc[mt][nt], 0, 0, 0);
  }
#undef GEMM_ISSUE
}

// ---------------- fused projection GEMMs ----------------
template <int REF>
__global__ __launch_bounds__(256) void gemm_fused(
    const ushort* __restrict__ A, const ushort* __restrict__ W,
    const float* __restrict__ bA, const float* __restrict__ bB,
    const float* __restrict__ bC,
    ushort* __restrict__ oA, ushort* __restrict__ oB, ushort* __restrict__ oC) {
  const int bm = blockIdx.x, bn = blockIdx.y;
  const int tid = threadIdx.x;
  const int w = tid >> 6, lane = tid & 63, quad = lane >> 4, l16 = lane & 15;
  const int mw = (w >> 1) * 64, nw = (w & 1) * 64;

  __shared__ __align__(16) ushort As[2 * 4096];
  __shared__ __align__(16) ushort Bs[2 * 4096];

  floatx4 acc[4][4];
#pragma unroll
  for (int mt = 0; mt < 4; ++mt)
#pragma unroll
    for (int nt = 0; nt < 4; ++nt) acc[mt][nt] = (floatx4){0.f, 0.f, 0.f, 0.f};

  gemm_core(A + (size_t)bm * 128 * 768, W + (size_t)bn * 128 * 768,
            As, Bs, tid, quad, l16, mw, nw, acc);

  const int sec = bn / 6;
  const float* bp = sec == 0 ? bA : sec == 1 ? bB : bC;
  ushort* op = sec == 0 ? oA : sec == 1 ? oB : oC;
  const bool qlay = (REF == 0 && sec == 0);
#pragma unroll
  for (int nt = 0; nt < 4; ++nt) {
    const int nloc = (bn - sec * 6) * 128 + nw + nt * 16 + l16;
    const float bv = bp[nloc];
    const int hh = nloc >> 6, dd = nloc & 63;
#pragma unroll
    for (int mt = 0; mt < 4; ++mt)
#pragma unroll
      for (int i = 0; i < 4; ++i) {
        const int m = bm * 128 + mw + mt * 16 + quad * 4 + i;
        int bb, tt;
        if (REF == 0) { bb = m >> 11; tt = m & 2047; }
        else { bb = m >> 9; tt = (m & 511) + 2048; }
        const size_t idx = qlay ? (((size_t)(bb * 12 + hh) * 2048 + tt) * 64 + dd)
                                : (((size_t)(bb * 12 + hh) * 2560 + tt) * 64 + dd);
        op[idx] = f2bf(acc[mt][nt][i] + bv);
      }
  }
}

// ---------------- output projection: fp32 out ----------------
__global__ __launch_bounds__(256) void gemm_out(
    const ushort* __restrict__ A, const ushort* __restrict__ W,
    const float* __restrict__ bias, float* __restrict__ out) {
  const int bm = blockIdx.x, bn = blockIdx.y;
  const int tid = threadIdx.x;
  const int w = tid >> 6, lane = tid & 63, quad = lane >> 4, l16 = lane & 15;
  const int mw = (w >> 1) * 64, nw = (w & 1) * 64;

  __shared__ __align__(16) ushort As[2 * 4096];
  __shared__ __align__(16) ushort Bs[2 * 4096];

  floatx4 acc[4][4];
#pragma unroll
  for (int mt = 0; mt < 4; ++mt)
#pragma unroll
    for (int nt = 0; nt < 4; ++nt) acc[mt][nt] = (floatx4){0.f, 0.f, 0.f, 0.f};

  gemm_core(A + (size_t)bm * 128 * 768, W + (size_t)bn * 128 * 768,
            As, Bs, tid, quad, l16, mw, nw, acc);

#pragma unroll
  for (int nt = 0; nt < 4; ++nt) {
    const int n = bn * 128 + nw + nt * 16 + l16;
    const float bv = bias[n];
#pragma unroll
    for (int mt = 0; mt < 4; ++mt)
#pragma unroll
      for (int i = 0; i < 4; ++i) {
        const int m = bm * 128 + mw + mt * 16 + quad * 4 + i;
        out[(size_t)m * 768 + n] = acc[mt][nt][i] + bv;
      }
  }
}

// ---------------- flash attention v4: gld16 K dbuf, V dbuf, 1 barrier/tile ----------------
// grid (B, T/64, H), 256 threads = 4 waves; wave w owns q-rows [w*16,w*16+16).
// S^T = K.Q^T (lane owns q-column l16). K staged by global_load_lds into a
// double buffer with XOR swizzle realized via per-lane global addresses
// (gld16 LDS dest is linear; we permute the SOURCE). V double-buffered through
// 2 uint4 regs + transpose-scatter. rel is per-wave-private LDS rows (no
// barrier); mask from prepacked bitwords. One __syncthreads per tile.
__global__ __launch_bounds__(256, 3) void attn(
    const ushort* __restrict__ qb, const ushort* __restrict__ kb,
    const ushort* __restrict__ vb, const unsigned long long* __restrict__ bits,
    const float* __restrict__ relp, ushort* __restrict__ yb) {
  const int b = blockIdx.x, qt = blockIdx.y, h = blockIdx.z;
  const int tid = threadIdx.x;
  const int w = tid >> 6, lane = tid & 63, quad = lane >> 4, l16 = lane & 15;

  __shared__ __align__(16) ushort Kl[2][64 * 64];  // [key][d], XOR-swizzled chunks
  __shared__ __align__(16) ushort Vl[2][64 * 64];  // [d][key'], xor chunk swizzle; Vl[1] holds Q pre-loop
  __shared__ __align__(16) ushort Rel[64 * 72];    // bf16 rel, per-wave-private rows
  __shared__ __align__(16) ushort Ps[4][16 * 72];  // per-wave P^T [qr][key]

  const ushort* qsrc = qb + ((size_t)(b * 12 + h) * 2048 + qt * 64) * 64;
  const ushort* ksrc = kb + (size_t)(b * 12 + h) * 2560 * 64;
  const ushort* vsrc = vb + (size_t)(b * 12 + h) * 2560 * 64;
  const int qrow = qt * 64 + w * 16 + l16;
  const unsigned long long* brow = bits + ((size_t)b * 2048 + qrow) * 32;
  const float* rbase = relp + ((size_t)h * 2048 + qt * 64) * 2048;

  const int krow = lane >> 3;                 // 0..7 within a gld16 call
  const int kchunk = (lane & 7) ^ krow;       // XOR-swizzled source chunk

  // ---- stage Q into Vl[1] (V(1) not written until it=1, bQ read pre-loop) ----
#pragma unroll
  for (int c = 0; c < 2; ++c) {
    const int f = tid + c * 256;
    *(uint4*)&Vl[1][(f >> 3) * 64 + (f & 7) * 8] = *(const uint4*)(qsrc + f * 8);
  }
  // ---- issue gld16 K(0) -> Kl[0] ----
#pragma unroll
  for (int c = 0; c < 2; ++c) {
    const int rb = w * 16 + c * 8;
    gld16(&Kl[0][rb * 64], ksrc + (rb + krow) * 64 + kchunk * 8);
  }
  // ---- prefetch V(0), rel(0), bits(0) into regs ----
  uint4 vd[2];
  float4 rd[4];
  unsigned long long bnext;
  vd[0] = *(const uint4*)(vsrc + tid * 8);
  vd[1] = *(const uint4*)(vsrc + (tid + 256) * 8);
#pragma unroll
  for (int p = 0; p < 4; ++p) {
    const int idx = lane + p * 64, rr = idx >> 4, c4 = idx & 15;
    rd[p] = *(const float4*)(rbase + (size_t)(w * 16 + rr) * 2048 + c4 * 4);
  }
  bnext = brow[0];

  __syncthreads();  // Q staged, K(0) drained
  bf16x8 bQ[2];
  bQ[0] = *(const bf16x8*)&Vl[1][(w * 16 + l16) * 64 + quad * 8];
  bQ[1] = *(const bf16x8*)&Vl[1][(w * 16 + l16) * 64 + 32 + quad * 8];

  floatx4 acc[4];
#pragma unroll
  for (int mt = 0; mt < 4; ++mt) acc[mt] = (floatx4){0.f, 0.f, 0.f, 0.f};
  float m_run = -__builtin_inff(), l_run = 0.f;

#pragma unroll 1
  for (int it = 0; it < 40; ++it) {
    const int p = it & 1;
    const bool self = it < 32;
    // ---- write V(it) -> Vl[p] (readers of it-1 use other parity) ----
#pragma unroll
    for (int c = 0; c < 2; ++c) {
      const int f = tid + c * 256;
      const int key = f >> 3, d0 = (f & 7) * 8;
      const int cb = (((key >> 3) ^ (f & 7)) & 7) * 8 + (key & 7);
      uint vv[4] = {vd[c].x, vd[c].y, vd[c].z, vd[c].w};
#pragma unroll
      for (int u = 0; u < 4; ++u) {
        Vl[p][(d0 + 2 * u) * 64 + cb] = (ushort)(vv[u] & 0xffffu);
        Vl[p][(d0 + 2 * u + 1) * 64 + cb] = (ushort)(vv[u] >> 16);
      }
    }
    // ---- write rel(it) -> own wave's rows (bf16) ----
    if (self) {
#pragma unroll
      for (int pp = 0; pp < 4; ++pp) {
        const int idx = lane + pp * 64, rr = idx >> 4, c4 = idx & 15;
        ushort4 o;
        o.x = f2bf(rd[pp].x); o.y = f2bf(rd[pp].y);
        o.z = f2bf(rd[pp].z); o.w = f2bf(rd[pp].w);
        *(ushort4*)&Rel[(w * 16 + rr) * 72 + c4 * 4] = o;
      }
    }
    const unsigned long long bcur = bnext;
    __syncthreads();  // K(it) drained (gld16), V(it)/rel visible; all waves past it-1

    // ---- prefetch tile it+1 (full compute phase to land) ----
    const int itn = it + 1;
    if (itn < 40) {
#pragma unroll
      for (int c = 0; c < 2; ++c) {
        const int rb = w * 16 + c * 8;
        gld16(&Kl[itn & 1][rb * 64], ksrc + (size_t)itn * 4096 + (rb + krow) * 64 + kchunk * 8);
      }
      const ushort* vt0 = vsrc + (size_t)itn * 4096;
      vd[0] = *(const uint4*)(vt0 + tid * 8);
      vd[1] = *(const uint4*)(vt0 + (tid + 256) * 8);
      if (itn < 32) {
#pragma unroll
        for (int pp = 0; pp < 4; ++pp) {
          const int idx = lane + pp * 64, rr = idx >> 4, c4 = idx & 15;
          rd[pp] = *(const float4*)(rbase + (size_t)(w * 16 + rr) * 2048 + itn * 64 + c4 * 4);
        }
        bnext = brow[itn];
      }
    }

    // ---- S^T = K.Q^T : lane holds S^T[key = mt*16+quad*4+i][qr=l16] ----
    floatx4 st[4];
#pragma unroll
    for (int mt = 0; mt < 4; ++mt) st[mt] = (floatx4){0.f, 0.f, 0.f, 0.f};
#pragma unroll
    for (int kk = 0; kk < 2; ++kk)
#pragma unroll
      for (int mt = 0; mt < 4; ++mt) {
        const bf16x8 aK = *(const bf16x8*)
            &Kl[p][(mt * 16 + l16) * 64 + (((kk * 4 + quad) ^ (l16 & 7)) * 8)];
        st[mt] = __builtin_amdgcn_mfma_f32_16x16x32_bf16(aK, bQ[kk], st[mt], 0, 0, 0);
      }
    // ---- scale + rel + mask ----
#pragma unroll
    for (int mt = 0; mt < 4; ++mt) {
      if (self) {
        const ushort4 rv4 = *(const ushort4*)&Rel[(w * 16 + l16) * 72 + mt * 16 + quad * 4];
        const ushort rv[4] = {rv4.x, rv4.y, rv4.z, rv4.w};
#pragma unroll
        for (int i = 0; i < 4; ++i) {
          const float sv = st[mt][i] * 0.125f + bf2f(rv[i]);
          const int bit = mt * 16 + quad * 4 + i;
          st[mt][i] = ((bcur >> bit) & 1ull) ? -__builtin_inff() : sv;
        }
      } else {
#pragma unroll
        for (int i = 0; i < 4; ++i) st[mt][i] *= 0.125f;
      }
    }
    // ---- online softmax (per q-column l16) ----
    float tm = st[0][0];
#pragma unroll
    for (int mt = 0; mt < 4; ++mt)
#pragma unroll
      for (int i = 0; i < 4; ++i) tm = fmaxf(tm, st[mt][i]);
    tm = fmaxf(tm, __shfl_xor(tm, 16));
    tm = fmaxf(tm, __shfl_xor(tm, 32));
    const float mnew = fmaxf(m_run, tm);
    const float mref = (mnew == -__builtin_inff()) ? 0.f : mnew;
    const float alpha = (m_run == -__builtin_inff()) ? 0.f : __expf(m_run - mnew);
    float rs = 0.f;
#pragma unroll
    for (int mt = 0; mt < 4; ++mt)
#pragma unroll
      for (int i = 0; i < 4; ++i) {
        const float pv = __expf(st[mt][i] - mref);
        st[mt][i] = pv;
        rs += pv;
      }
    rs += __shfl_xor(rs, 16);
    rs += __shfl_xor(rs, 32);
    l_run = l_run * alpha + rs;
    m_run = mnew;
#pragma unroll
    for (int mt = 0; mt < 4; ++mt)
#pragma unroll
      for (int i = 0; i < 4; ++i) acc[mt][i] *= alpha;

    // ---- P^T -> own wave's Ps rows ----
    {
      ushort* pw = &Ps[w][l16 * 72 + quad * 4];
#pragma unroll
      for (int mt = 0; mt < 4; ++mt) {
        const uint pk0 = (uint)f2bf(st[mt][0]) | ((uint)f2bf(st[mt][1]) << 16);
        const uint pk1 = (uint)f2bf(st[mt][2]) | ((uint)f2bf(st[mt][3]) << 16);
        *(uint*)&pw[mt * 16] = pk0;
        *(uint*)&pw[mt * 16 + 2] = pk1;
      }
    }
    // ---- O^T += V^T . P^T ----
#pragma unroll
    for (int kk = 0; kk < 2; ++kk) {
      const bf16x8 bP = *(const bf16x8*)&Ps[w][l16 * 72 + kk * 32 + quad * 8];
#pragma unroll
      for (int mt = 0; mt < 4; ++mt) {
        const int dd = mt * 16 + l16;
        const int cs = (((kk * 4 + quad) ^ (dd >> 3)) & 7) * 8;
        const bf16x8 aV = *(const bf16x8*)&Vl[p][dd * 64 + cs];
        acc[mt] = __builtin_amdgcn_mfma_f32_16x16x32_bf16(aV, bP, acc[mt], 0, 0, 0);
      }
    }
  }

  // ---- epilogue: y[b][t][h*64+d] bf16 ----
  const float inv = 1.f / l_run;
  ushort* yrow = yb + ((size_t)b * 2048 + qt * 64 + w * 16 + l16) * 768 + h * 64;
#pragma unroll
  for (int mt = 0; mt < 4; ++mt)
#pragma unroll
    for (int i = 0; i < 4; ++i)
      yrow[mt * 16 + quad * 4 + i] = f2bf(acc[mt][i] * inv);
}

// ---------------- launch ----------------
extern "C" void kernel_launch(void* const* d_in, const int* in_sizes, int n_in,
                              void* d_out, int out_size, void* d_ws, size_t ws_size,
                              hipStream_t stream) {
  const float* x = (const float*)d_in[0];
  const int* mask = (const int*)d_in[1];
  const float* relp = (const float*)d_in[2];
  const float* ref = (const float*)d_in[3];
  const float* Wq = (const float*)d_in[4];
  const float* bq = (const float*)d_in[5];
  const float* Wk = (const float*)d_in[6];
  const float* bk = (const float*)d_in[7];
  const float* Wv = (const float*)d_in[8];
  const float* bv = (const float*)d_in[9];
  const float* Wrk = (const float*)d_in[10];
  const float* brk = (const float*)d_in[11];
  const float* Wrv = (const float*)d_in[12];
  const float* brv = (const float*)d_in[13];
  const float* Wo = (const float*)d_in[14];
  const float* bo = (const float*)d_in[15];

  ushort* xb = (ushort*)d_ws;                 // 3,145,728
  ushort* refb = xb + 3145728;                // 786,432
  ushort* wb = refb + 786432;                 // 6 * 589,824  (q,k,v,rk,rv,o)
  ushort* qbuf = wb + 6 * 589824;             // 3,145,728   [b][h][t][d]
  ushort* kbuf = qbuf + 3145728;              // 3,932,160   [b][h][key][d], L=2560
  ushort* vbuf = kbuf + 3932160;              // 3,932,160
  ushort* ybuf = vbuf + 3932160;              // 3,145,728   [b][t][c]
  unsigned long long* bitsbuf = (unsigned long long*)(ybuf + 3145728);  // 131072 u64

  cast_all<<<7296, 256, 0, stream>>>(x, ref, Wq, Wk, Wv, Wrk, Wrv, Wo, xb);
  pack_mask<<<512, 256, 0, stream>>>(mask, bitsbuf);

  gemm_fused<0><<<dim3(32, 18), 256, 0, stream>>>(
      xb, wb, bq, bk, bv, qbuf, kbuf, vbuf);
  gemm_fused<1><<<dim3(8, 12), 256, 0, stream>>>(
      refb, wb + (size_t)3 * 589824, brk, brv, nullptr, kbuf, vbuf, nullptr);

  attn<<<dim3(2, 32, 12), 256, 0, stream>>>(qbuf, kbuf, vbuf, bitsbuf, relp, ybuf);

  gemm_out<<<dim3(32, 6), 256, 0, stream>>>(
      ybuf, wb + (size_t)5 * 589824, bo, (float*)d_out);
}